// Round 3
// baseline (129.206 us; speedup 1.0000x reference)
//
#include <hip/hip_runtime.h>

#define H   768
#define Hh  384
#define LL  192
#define RR  24
#define HH  589824   // 768*768

typedef __attribute__((ext_vector_type(8))) short bf16x8;
typedef __attribute__((ext_vector_type(4))) float f32x4;

__device__ __forceinline__ unsigned short f2bf(float f) {
    unsigned int u = __float_as_uint(f);
    return (unsigned short)((u + 0x7FFF + ((u >> 16) & 1)) >> 16);  // RNE
}

__device__ __forceinline__ void gload16(const void* g, void* l) {
    __builtin_amdgcn_global_load_lds(
        (const __attribute__((address_space(1))) unsigned int*)g,
        (__attribute__((address_space(3))) unsigned int*)l, 16, 0, 0);
}

// ---------------------------------------------------------------------------
// k_pre: grid 1056 x 256
//   0..23    : masked avg pool (4b x 6 h-chunks)           -> avg_ws
//   24..47   : rp[b][n] = rel_e . W_tag[:H] + b_tag        -> rp_ws
//   48..191  : emb -> bf16                                  -> embh
//   192..1055: W_corr[:H], W_corr[H:], W_tag[H:] -> bf16 transposed [n][k]
// ---------------------------------------------------------------------------
__global__ __launch_bounds__(256) void k_pre(
    const float* __restrict__ emb, const int* __restrict__ mask,
    const int* __restrict__ target_rel,
    const float* __restrict__ W_corr, const float* __restrict__ W_tag,
    const float* __restrict__ b_tag, const float* __restrict__ rel_emb,
    float* __restrict__ avg_ws, float* __restrict__ rp_ws,
    unsigned short* __restrict__ embh, unsigned short* __restrict__ wct0,
    unsigned short* __restrict__ wct1, unsigned short* __restrict__ wtt)
{
    const int bid = blockIdx.x, tid = threadIdx.x;

    if (bid < 24) {
        // ---- masked average pool ----
        __shared__ float msk[LL];
        __shared__ float part[32];
        __shared__ float msumS;
        __shared__ float4 red4[8][32];
        const int b  = bid / 6;
        const int h0 = (bid % 6) * 128;
        const int tx = tid & 31, ty = tid >> 5;
        if (tid < LL) msk[tid] = (float)mask[b * LL + tid];
        __syncthreads();
        if (tid < 32) {
            float s = 0.f;
            for (int k = tid; k < LL; k += 32) s += msk[k];
            part[tid] = s;
        }
        __syncthreads();
        if (tid == 0) {
            float s = 0.f;
            for (int k = 0; k < 32; ++k) s += part[k];
            msumS = s;
        }
        float4 acc = make_float4(0.f, 0.f, 0.f, 0.f);
        for (int l = ty; l < LL; l += 8) {
            const float m = msk[l];
            const float4 v = *(const float4*)(emb + (size_t)(b * LL + l) * H + h0 + tx * 4);
            acc.x += v.x * m; acc.y += v.y * m; acc.z += v.z * m; acc.w += v.w * m;
        }
        red4[ty][tx] = acc;
        __syncthreads();
        if (tid < 32) {
            float4 s = red4[0][tid];
#pragma unroll
            for (int r = 1; r < 8; ++r) {
                s.x += red4[r][tid].x; s.y += red4[r][tid].y;
                s.z += red4[r][tid].z; s.w += red4[r][tid].w;
            }
            const float inv = 1.f / msumS;
            s.x *= inv; s.y *= inv; s.z *= inv; s.w *= inv;
            *(float4*)(avg_ws + (size_t)b * H + h0 + tid * 4) = s;
        }
        return;
    }

    if (bid < 48) {
        // ---- rp[b][n] = sum_h rel_e[h]*W_tag[h][n] + b_tag[n] ----
        __shared__ float rps[2][128];
        const int rb = bid - 24;
        const int b  = rb / 6;
        const int n0 = (rb % 6) * 128;
        const int n  = n0 + (tid & 127), half = tid >> 7;
        const float* re = rel_emb + (size_t)target_rel[b] * H;
        float s = 0.f;
        for (int h = half * 384; h < half * 384 + 384; ++h)
            s += re[h] * W_tag[(size_t)h * H + n];
        rps[half][tid & 127] = s;
        __syncthreads();
        if (tid < 128)
            rp_ws[(size_t)b * H + n0 + tid] = rps[0][tid] + rps[1][tid] + b_tag[n0 + tid];
        return;
    }

    if (bid < 192) {
        // ---- emb -> bf16, 16 elems/thread ----
        const size_t t = (size_t)(bid - 48) * 256 + tid;
        const float* s = emb + t * 16;
        union { unsigned short u[16]; uint4 v[2]; } pk;
#pragma unroll
        for (int q = 0; q < 4; ++q) {
            const float4 v = *(const float4*)(s + q * 4);
            pk.u[q * 4 + 0] = f2bf(v.x); pk.u[q * 4 + 1] = f2bf(v.y);
            pk.u[q * 4 + 2] = f2bf(v.z); pk.u[q * 4 + 3] = f2bf(v.w);
        }
        *(uint4*)(embh + t * 16)     = pk.v[0];
        *(uint4*)(embh + t * 16 + 8) = pk.v[1];
        return;
    }

    // ---- weight transpose + bf16: Wt[n][k] = W[k][n] ----
    const int local = bid - 192;          // 0..863
    const int m  = local / 288;           // which matrix
    const int r2 = local % 288;
    const int ko = r2 / 3, nb = r2 % 3;
    const int n  = nb * 256 + tid;
    const float* src = (m == 0) ? W_corr : (m == 1) ? W_corr + HH : W_tag + HH;
    unsigned short* dst = (m == 0) ? wct0 : (m == 1) ? wct1 : wtt;
    union { unsigned short u[8]; uint4 v; } pk;
#pragma unroll
    for (int q = 0; q < 8; ++q)
        pk.u[q] = f2bf(src[(size_t)(ko * 8 + q) * H + n]);
    *(uint4*)(dst + (size_t)n * H + ko * 8) = pk.v;
}

// ---------------------------------------------------------------------------
// k_main: grid 133 x 256
//   0..107 : bf16 MFMA GEMM, 128x128 tile, BK=32, dbuf LDS, gload_lds(16B)
//            sel = nt/6: 0 -> hfb(+b_corr), 1 -> hsb, 2 -> fusb
//   108..131: relh GEMV (fp32)
//   132    : tagbias[b][6] = rp_b . W_{sub,obj} + b_{sub,obj}
// ---------------------------------------------------------------------------
__global__ __launch_bounds__(256) void k_main(
    const unsigned short* __restrict__ embh, const unsigned short* __restrict__ wct0,
    const unsigned short* __restrict__ wct1, const unsigned short* __restrict__ wtt,
    const float* __restrict__ b_corr,
    const float* __restrict__ W_relh, const float* __restrict__ b_relh,
    const float* __restrict__ avg_ws, const float* __restrict__ rp_ws,
    const float* __restrict__ W_sub, const float* __restrict__ b_sub,
    const float* __restrict__ W_obj, const float* __restrict__ b_obj,
    float* __restrict__ hfb, float* __restrict__ hsb, float* __restrict__ fusb,
    float* __restrict__ relh_ws, float* __restrict__ tagbias_ws)
{
    const int bid = blockIdx.x, tid = threadIdx.x;

    if (bid >= 108) {
        if (bid < 132) {
            // ---- relh GEMV ----
            __shared__ float avgS[H];
            __shared__ float redr[4][64];
            const int rb = bid - 108;
            const int b  = rb / 6;
            const int o0 = (rb % 6) * 64;
            const int tx = tid & 63, ty = tid >> 6;
            for (int i = tid; i < H; i += 256) avgS[i] = avg_ws[(size_t)b * H + i];
            __syncthreads();
            float s = 0.f;
            for (int k = ty; k < H; k += 4)
                s += avgS[k] * W_relh[(size_t)k * Hh + o0 + tx];
            redr[ty][tx] = s;
            __syncthreads();
            if (ty == 0) {
                float r = redr[0][tx] + redr[1][tx] + redr[2][tx] + redr[3][tx];
                relh_ws[(size_t)b * Hh + o0 + tx] = fmaxf(r + b_relh[o0 + tx], 0.f);
            }
        } else {
            // ---- tagbias ----
            const int b = tid >> 6, ln = tid & 63;
            float a0 = 0, a1 = 0, a2 = 0, a3 = 0, a4 = 0, a5 = 0;
            for (int n = ln; n < H; n += 64) {
                const float rv = rp_ws[(size_t)b * H + n];
                a0 += rv * W_sub[n * 3 + 0]; a1 += rv * W_sub[n * 3 + 1];
                a2 += rv * W_sub[n * 3 + 2]; a3 += rv * W_obj[n * 3 + 0];
                a4 += rv * W_obj[n * 3 + 1]; a5 += rv * W_obj[n * 3 + 2];
            }
#pragma unroll
            for (int off = 32; off > 0; off >>= 1) {
                a0 += __shfl_down(a0, off); a1 += __shfl_down(a1, off);
                a2 += __shfl_down(a2, off); a3 += __shfl_down(a3, off);
                a4 += __shfl_down(a4, off); a5 += __shfl_down(a5, off);
            }
            if (ln == 0) {
                tagbias_ws[b * 6 + 0] = a0 + b_sub[0];
                tagbias_ws[b * 6 + 1] = a1 + b_sub[1];
                tagbias_ws[b * 6 + 2] = a2 + b_sub[2];
                tagbias_ws[b * 6 + 3] = a3 + b_obj[0];
                tagbias_ws[b * 6 + 4] = a4 + b_obj[1];
                tagbias_ws[b * 6 + 5] = a5 + b_obj[2];
            }
        }
        return;
    }

    // ------------------ MFMA GEMM ------------------
    __shared__ unsigned short As[2][128 * 32];
    __shared__ unsigned short Bs[2][128 * 32];
    const int mt = bid % 6, nt = bid / 6;
    const int sel = nt / 6, n0l = (nt % 6) * 128, m0 = mt * 128;
    const unsigned short* Bsrc = (sel == 0) ? wct0 : (sel == 1) ? wct1 : wtt;
    float* C = (sel == 0) ? hfb : (sel == 1) ? hsb : fusb;

    const int wv = tid >> 6, ln = tid & 63;
    const int ko = ln >> 4, lr = ln & 15;
    const int wr = (wv >> 1) * 64, wc = (wv & 1) * 64;

    f32x4 acc[4][4];
#pragma unroll
    for (int mi = 0; mi < 4; ++mi)
#pragma unroll
        for (int ni = 0; ni < 4; ++ni)
            acc[mi][ni] = (f32x4){0.f, 0.f, 0.f, 0.f};

    auto stage = [&](int buf, int k0) {
#pragma unroll
        for (int it = 0; it < 2; ++it) {
            const int slot = it * 256 + wv * 64 + ln;
            const int r = slot >> 2, s0 = slot & 3;
            const int s = s0 ^ ((r >> 1) & 3);
            gload16(embh + (size_t)(m0 + r) * H + k0 + s * 8,
                    &As[buf][(it * 256 + wv * 64) * 8]);
            gload16(Bsrc + (size_t)(n0l + r) * H + k0 + s * 8,
                    &Bs[buf][(it * 256 + wv * 64) * 8]);
        }
    };

    stage(0, 0);
    int cur = 0;
    for (int ks = 0; ks < 24; ++ks) {
        __syncthreads();
        if (ks < 23) stage(cur ^ 1, (ks + 1) * 32);
        const unsigned short* Ab = As[cur];
        const unsigned short* Bb = Bs[cur];
        bf16x8 af[4], bfr[4];
#pragma unroll
        for (int mi = 0; mi < 4; ++mi) {
            const int r = wr + mi * 16 + lr;
            af[mi] = *(const bf16x8*)(Ab + r * 32 + ((ko ^ ((r >> 1) & 3)) * 8));
        }
#pragma unroll
        for (int ni = 0; ni < 4; ++ni) {
            const int r = wc + ni * 16 + lr;
            bfr[ni] = *(const bf16x8*)(Bb + r * 32 + ((ko ^ ((r >> 1) & 3)) * 8));
        }
#pragma unroll
        for (int mi = 0; mi < 4; ++mi)
#pragma unroll
            for (int ni = 0; ni < 4; ++ni)
                acc[mi][ni] = __builtin_amdgcn_mfma_f32_16x16x32_bf16(
                    af[mi], bfr[ni], acc[mi][ni], 0, 0, 0);
        cur ^= 1;
    }

    float cb[4];
#pragma unroll
    for (int ni = 0; ni < 4; ++ni)
        cb[ni] = (sel == 0) ? b_corr[n0l + wc + ni * 16 + lr] : 0.f;
#pragma unroll
    for (int mi = 0; mi < 4; ++mi) {
#pragma unroll
        for (int ni = 0; ni < 4; ++ni) {
            const int m = m0 + wr + mi * 16 + ko * 4;
            const int n = n0l + wc + ni * 16 + lr;
#pragma unroll
            for (int r = 0; r < 4; ++r)
                C[(size_t)(m + r) * H + n] = acc[mi][ni][r] + cb[ni];
        }
    }
}

// ---------------------------------------------------------------------------
// k_tail: grid 241 x 512
//   0..143 : corres 16i x 64j tiles (4b x 12 x 3), 2 j/thread
//   144..239: tag heads, 8 rows/block (one wave each)
//   240    : stage1 = relh @ W_rj + b_rj
// ---------------------------------------------------------------------------
__global__ __launch_bounds__(512) void k_tail(
    const float* __restrict__ hfb, const float* __restrict__ hsb,
    const float* __restrict__ fusb, const float* __restrict__ relh_ws,
    const float* __restrict__ tagbias_ws,
    const float* __restrict__ W_gc, const float* __restrict__ b_gc,
    const float* __restrict__ W_rj, const float* __restrict__ b_rj,
    const float* __restrict__ W_sub, const float* __restrict__ W_obj,
    float* __restrict__ out)
{
    const int bid = blockIdx.x, tid = threadIdx.x;

    if (bid < 144) {
        __shared__ float hfT[32][68];   // [kk][j]
        __shared__ float hsS[16][36];   // [i][kk]
        const int b   = bid / 36;
        const int rem = bid % 36;
        const int i0  = (rem / 3) * 16;
        const int j0  = (rem % 3) * 64;
        const int ty = tid >> 5, tx = tid & 31;     // i = i0+ty, j = j0+tx*2
        const int jr = tid >> 3, q8 = tid & 7;      // staging
        float acc0 = 0.f, acc1 = 0.f;

        for (int hc = 0; hc < H; hc += 32) {
            const float4 fv = *(const float4*)(hfb + (size_t)(b * LL + j0 + jr) * H + hc + q8 * 4);
            hfT[q8 * 4 + 0][jr] = fv.x;
            hfT[q8 * 4 + 1][jr] = fv.y;
            hfT[q8 * 4 + 2][jr] = fv.z;
            hfT[q8 * 4 + 3][jr] = fv.w;
            if (tid < 128) {
                const float4 sv = *(const float4*)(hsb + (size_t)(b * LL + i0 + jr) * H + hc + q8 * 4);
                *(float4*)&hsS[jr][q8 * 4] = sv;
            }
            __syncthreads();
#pragma unroll
            for (int kq = 0; kq < 8; ++kq) {
                const float4 s4 = *(const float4*)&hsS[ty][kq * 4];
                const float4 w4 = *(const float4*)(W_gc + hc + kq * 4);
#pragma unroll
                for (int x = 0; x < 4; ++x) {
                    const float2 f2 = *(const float2*)&hfT[kq * 4 + x][tx * 2];
                    const float sv = (&s4.x)[x];
                    const float wv = (&w4.x)[x];
                    acc0 += fmaxf(f2.x + sv, 0.f) * wv;
                    acc1 += fmaxf(f2.y + sv, 0.f) * wv;
                }
            }
            __syncthreads();
        }
        const float bg = b_gc[0];
        float* po = out + 4704 + (size_t)b * LL * LL + (size_t)(i0 + ty) * LL + j0 + tx * 2;
        po[0] = acc0 + bg;
        po[1] = acc1 + bg;
    } else if (bid < 240) {
        // ---- tag heads ----
        const int wave = tid >> 6, lane = tid & 63;
        const int r = (bid - 144) * 8 + wave;
        const int b = r / LL;
        float a0 = 0, a1 = 0, a2 = 0, a3 = 0, a4 = 0, a5 = 0;
        for (int h = lane; h < H; h += 64) {
            const float f = fusb[(size_t)r * H + h];
            a0 += f * W_sub[h * 3 + 0]; a1 += f * W_sub[h * 3 + 1];
            a2 += f * W_sub[h * 3 + 2]; a3 += f * W_obj[h * 3 + 0];
            a4 += f * W_obj[h * 3 + 1]; a5 += f * W_obj[h * 3 + 2];
        }
#pragma unroll
        for (int off = 32; off > 0; off >>= 1) {
            a0 += __shfl_down(a0, off); a1 += __shfl_down(a1, off);
            a2 += __shfl_down(a2, off); a3 += __shfl_down(a3, off);
            a4 += __shfl_down(a4, off); a5 += __shfl_down(a5, off);
        }
        if (lane == 0) {
            out[96 + r * 3 + 0]   = a0 + tagbias_ws[b * 6 + 0];
            out[96 + r * 3 + 1]   = a1 + tagbias_ws[b * 6 + 1];
            out[96 + r * 3 + 2]   = a2 + tagbias_ws[b * 6 + 2];
            out[2400 + r * 3 + 0] = a3 + tagbias_ws[b * 6 + 3];
            out[2400 + r * 3 + 1] = a4 + tagbias_ws[b * 6 + 4];
            out[2400 + r * 3 + 2] = a5 + tagbias_ws[b * 6 + 5];
        }
    } else {
        // ---- stage1 phase B ----
        if (tid < 96) {
            const int b = tid / RR, rj = tid % RR;
            float s = b_rj[rj];
            for (int h = 0; h < Hh; ++h)
                s += relh_ws[b * Hh + h] * W_rj[h * RR + rj];
            out[b * RR + rj] = s;
        }
    }
}

extern "C" void kernel_launch(void* const* d_in, const int* in_sizes, int n_in,
                              void* d_out, int out_size, void* d_ws, size_t ws_size,
                              hipStream_t stream) {
    const float* emb    = (const float*)d_in[0];
    const int*   mask   = (const int*)d_in[1];
    const int*   trel   = (const int*)d_in[2];
    const float* W_relh = (const float*)d_in[3];
    const float* b_relh = (const float*)d_in[4];
    const float* W_rj   = (const float*)d_in[5];
    const float* b_rj   = (const float*)d_in[6];
    const float* W_corr = (const float*)d_in[7];
    const float* b_corr = (const float*)d_in[8];
    const float* W_gc   = (const float*)d_in[9];
    const float* b_gc   = (const float*)d_in[10];
    const float* relemb = (const float*)d_in[11];
    const float* W_tag  = (const float*)d_in[12];
    const float* b_tag  = (const float*)d_in[13];
    const float* W_sub  = (const float*)d_in[14];
    const float* b_sub  = (const float*)d_in[15];
    const float* W_obj  = (const float*)d_in[16];
    const float* b_obj  = (const float*)d_in[17];

    float* out = (float*)d_out;
    float* ws  = (float*)d_ws;
    float* hfb  = ws;                 // 768*768 f32
    float* hsb  = ws + (size_t)HH;    // 768*768 f32
    float* fusb = ws + (size_t)2 * HH;
    unsigned short* embh = (unsigned short*)(ws + (size_t)3 * HH);  // 768*768 bf16
    unsigned short* wct0 = embh + (size_t)HH;
    unsigned short* wct1 = wct0 + (size_t)HH;
    unsigned short* wtt  = wct1 + (size_t)HH;
    float* avg_ws     = ws + (size_t)3 * HH + 2 * HH;  // 4*768  (2*HH floats = 4*HH ushorts)
    float* relh_ws    = avg_ws + 4 * H;                // 4*384
    float* rp_ws      = relh_ws + 4 * Hh;              // 4*768
    float* tagbias_ws = rp_ws + 4 * H;                 // 4*6

    k_pre<<<1056, 256, 0, stream>>>(emb, mask, trel, W_corr, W_tag, b_tag, relemb,
                                    avg_ws, rp_ws, embh, wct0, wct1, wtt);
    k_main<<<133, 256, 0, stream>>>(embh, wct0, wct1, wtt, b_corr,
                                    W_relh, b_relh, avg_ws, rp_ws,
                                    W_sub, b_sub, W_obj, b_obj,
                                    hfb, hsb, fusb, relh_ws, tagbias_ws);
    k_tail<<<241, 512, 0, stream>>>(hfb, hsb, fusb, relh_ws, tagbias_ws,
                                    W_gc, b_gc, W_rj, b_rj,
                                    W_sub, W_obj, out);
}

// Round 4
// 84.644 us; speedup vs baseline: 1.5265x; 1.5265x over previous
//
#include <hip/hip_runtime.h>

#define H   768
#define Hh  384
#define LL  192
#define RR  24
#define HH  589824   // 768*768

typedef __attribute__((ext_vector_type(8))) short bf16x8;
typedef __attribute__((ext_vector_type(4))) float f32x4;

__device__ __forceinline__ unsigned short f2bf(float f) {
    unsigned int u = __float_as_uint(f);
    return (unsigned short)((u + 0x7FFF + ((u >> 16) & 1)) >> 16);  // RNE
}

__device__ __forceinline__ void gload16(const void* g, void* l) {
    __builtin_amdgcn_global_load_lds(
        (const __attribute__((address_space(1))) unsigned int*)g,
        (__attribute__((address_space(3))) unsigned int*)l, 16, 0, 0);
}

// ---------------------------------------------------------------------------
// k_pre: grid 1224 x 256
//   [0,24)     : masked avg pool (4b x 6 h-chunks)          -> avg_ws
//   [24,216)   : rp partials (k-split x8)                    -> rp_part
//   [216,360)  : emb -> bf16                                 -> embh
//   [360,1224) : weights -> bf16 transposed [n][k]           -> wct0/wct1/wtt
// ---------------------------------------------------------------------------
__global__ __launch_bounds__(256) void k_pre(
    const float* __restrict__ emb, const int* __restrict__ mask,
    const int* __restrict__ target_rel,
    const float* __restrict__ W_corr, const float* __restrict__ W_tag,
    const float* __restrict__ rel_emb,
    float* __restrict__ avg_ws, float* __restrict__ rp_part,
    unsigned short* __restrict__ embh, unsigned short* __restrict__ wct0,
    unsigned short* __restrict__ wct1, unsigned short* __restrict__ wtt)
{
    const int bid = blockIdx.x, tid = threadIdx.x;

    if (bid < 24) {
        __shared__ float msk[LL];
        __shared__ float part[32];
        __shared__ float msumS;
        __shared__ float4 red4[8][32];
        const int b  = bid / 6;
        const int h0 = (bid % 6) * 128;
        const int tx = tid & 31, ty = tid >> 5;
        if (tid < LL) msk[tid] = (float)mask[b * LL + tid];
        __syncthreads();
        if (tid < 32) {
            float s = 0.f;
            for (int k = tid; k < LL; k += 32) s += msk[k];
            part[tid] = s;
        }
        __syncthreads();
        if (tid == 0) {
            float s = 0.f;
            for (int k = 0; k < 32; ++k) s += part[k];
            msumS = s;
        }
        float4 acc = make_float4(0.f, 0.f, 0.f, 0.f);
        for (int l = ty; l < LL; l += 8) {
            const float m = msk[l];
            const float4 v = *(const float4*)(emb + (size_t)(b * LL + l) * H + h0 + tx * 4);
            acc.x += v.x * m; acc.y += v.y * m; acc.z += v.z * m; acc.w += v.w * m;
        }
        red4[ty][tx] = acc;
        __syncthreads();
        if (tid < 32) {
            float4 s = red4[0][tid];
#pragma unroll
            for (int r = 1; r < 8; ++r) {
                s.x += red4[r][tid].x; s.y += red4[r][tid].y;
                s.z += red4[r][tid].z; s.w += red4[r][tid].w;
            }
            const float inv = 1.f / msumS;
            s.x *= inv; s.y *= inv; s.z *= inv; s.w *= inv;
            *(float4*)(avg_ws + (size_t)b * H + h0 + tid * 4) = s;
        }
        return;
    }

    if (bid < 216) {
        // rp_part[(kc*4+b)*H + n] = sum_{h in 96-chunk kc} rel_e[h]*W_tag[h][n]
        __shared__ float red2[2][128];
        const int rb = bid - 24;
        const int kc = rb & 7;
        const int t2 = rb >> 3;          // 0..23
        const int b  = t2 / 6;
        const int n0 = (t2 % 6) * 128;
        const int n  = n0 + (tid & 127);
        const int strip = tid >> 7;      // 0..1, 48 rows each
        const float* re = rel_emb + (size_t)target_rel[b] * H;
        const int h0 = kc * 96 + strip * 48;
        float s = 0.f;
        for (int h = h0; h < h0 + 48; ++h)
            s += re[h] * W_tag[(size_t)h * H + n];
        red2[strip][tid & 127] = s;
        __syncthreads();
        if (tid < 128)
            rp_part[(size_t)(kc * 4 + b) * H + n0 + tid] = red2[0][tid] + red2[1][tid];
        return;
    }

    if (bid < 360) {
        // emb -> bf16, 16 elems/thread
        const size_t t = (size_t)(bid - 216) * 256 + tid;
        const float* s = emb + t * 16;
        union { unsigned short u[16]; uint4 v[2]; } pk;
#pragma unroll
        for (int q = 0; q < 4; ++q) {
            const float4 v = *(const float4*)(s + q * 4);
            pk.u[q * 4 + 0] = f2bf(v.x); pk.u[q * 4 + 1] = f2bf(v.y);
            pk.u[q * 4 + 2] = f2bf(v.z); pk.u[q * 4 + 3] = f2bf(v.w);
        }
        *(uint4*)(embh + t * 16)     = pk.v[0];
        *(uint4*)(embh + t * 16 + 8) = pk.v[1];
        return;
    }

    // weight transpose + bf16: Wt[n][k] = W[k][n]
    const int local = bid - 360;          // 0..863
    const int m  = local / 288;
    const int r2 = local % 288;
    const int ko = r2 / 3, nb = r2 % 3;
    const int n  = nb * 256 + tid;
    const float* src = (m == 0) ? W_corr : (m == 1) ? W_corr + HH : W_tag + HH;
    unsigned short* dst = (m == 0) ? wct0 : (m == 1) ? wct1 : wtt;
    union { unsigned short u[8]; uint4 v; } pk;
#pragma unroll
    for (int q = 0; q < 8; ++q)
        pk.u[q] = f2bf(src[(size_t)(ko * 8 + q) * H + n]);
    *(uint4*)(dst + (size_t)n * H + ko * 8) = pk.v;
}

// ---------------------------------------------------------------------------
// k_main: grid 625 x 256
//   [0,432)   : bf16 MFMA GEMM, 64x64 tile, BK=64, dbuf, XOR-swizzled staging
//               sel = bid/144: 0 -> hfb(+b_corr), 1 -> hsb, 2 -> fusb
//   [432,624) : relh partials (k-split x8)                   -> relh_part
//   624       : tagbias[b][6] from rp_part + W_sub/W_obj
// ---------------------------------------------------------------------------
__global__ __launch_bounds__(256) void k_main(
    const unsigned short* __restrict__ embh, const unsigned short* __restrict__ wct0,
    const unsigned short* __restrict__ wct1, const unsigned short* __restrict__ wtt,
    const float* __restrict__ b_corr,
    const float* __restrict__ W_relh, const float* __restrict__ avg_ws,
    const float* __restrict__ rp_part, const float* __restrict__ b_tag,
    const float* __restrict__ W_sub, const float* __restrict__ b_sub,
    const float* __restrict__ W_obj, const float* __restrict__ b_obj,
    float* __restrict__ hfb, float* __restrict__ hsb, float* __restrict__ fusb,
    float* __restrict__ relh_part, float* __restrict__ tagbias_ws)
{
    __shared__ unsigned short As[2][4096];
    __shared__ unsigned short Bs[2][4096];
    const int bid = blockIdx.x, tid = threadIdx.x;

    if (bid >= 432) {
        if (bid < 624) {
            // ---- relh partials: 24 k-rows per thread ----
            float* red = (float*)&As[0][0];   // [4][64]
            const int rb = bid - 432;
            const int kc = rb & 7;
            const int t2 = rb >> 3;          // 0..23
            const int b  = t2 / 6;
            const int o0 = (t2 % 6) * 64;
            const int tx = tid & 63, ty = tid >> 6;
            const int h0 = kc * 96 + ty * 24;
            float s = 0.f;
            for (int h = h0; h < h0 + 24; ++h)
                s += avg_ws[(size_t)b * H + h] * W_relh[(size_t)h * Hh + o0 + tx];
            red[ty * 64 + tx] = s;
            __syncthreads();
            if (ty == 0)
                relh_part[(size_t)(kc * 4 + b) * Hh + o0 + tx] =
                    red[tx] + red[64 + tx] + red[128 + tx] + red[192 + tx];
        } else {
            // ---- tagbias ----
            float* rpS = (float*)&As[0][0];   // [4*768] = 12 KB
            for (int i = tid; i < 4 * H; i += 256) {
                const int b2 = i / H, n = i % H;
                float rv = b_tag[n];
#pragma unroll
                for (int kc = 0; kc < 8; ++kc)
                    rv += rp_part[(size_t)(kc * 4 + b2) * H + n];
                rpS[i] = rv;
            }
            __syncthreads();
            const int b = tid >> 6, ln = tid & 63;
            float a0 = 0, a1 = 0, a2 = 0, a3 = 0, a4 = 0, a5 = 0;
            for (int n = ln; n < H; n += 64) {
                const float rv = rpS[b * H + n];
                a0 += rv * W_sub[n * 3 + 0]; a1 += rv * W_sub[n * 3 + 1];
                a2 += rv * W_sub[n * 3 + 2]; a3 += rv * W_obj[n * 3 + 0];
                a4 += rv * W_obj[n * 3 + 1]; a5 += rv * W_obj[n * 3 + 2];
            }
#pragma unroll
            for (int off = 32; off > 0; off >>= 1) {
                a0 += __shfl_down(a0, off); a1 += __shfl_down(a1, off);
                a2 += __shfl_down(a2, off); a3 += __shfl_down(a3, off);
                a4 += __shfl_down(a4, off); a5 += __shfl_down(a5, off);
            }
            if (ln == 0) {
                tagbias_ws[b * 6 + 0] = a0 + b_sub[0];
                tagbias_ws[b * 6 + 1] = a1 + b_sub[1];
                tagbias_ws[b * 6 + 2] = a2 + b_sub[2];
                tagbias_ws[b * 6 + 3] = a3 + b_obj[0];
                tagbias_ws[b * 6 + 4] = a4 + b_obj[1];
                tagbias_ws[b * 6 + 5] = a5 + b_obj[2];
            }
        }
        return;
    }

    // ------------------ MFMA GEMM: 64x64 tile, BK=64 ------------------
    const int sel = bid / 144;
    const int tt  = bid % 144;
    const int mt = tt % 12, nt = tt / 12;
    const int m0 = mt * 64, n0 = nt * 64;
    const unsigned short* Bsrc = (sel == 0) ? wct0 : (sel == 1) ? wct1 : wtt;
    float* C = (sel == 0) ? hfb : (sel == 1) ? hsb : fusb;

    const int wv = tid >> 6, ln = tid & 63;
    const int lr = ln & 15, ko = ln >> 4;
    const int wr = (wv >> 1) * 32, wc = (wv & 1) * 32;

    f32x4 acc[2][2];
#pragma unroll
    for (int mi = 0; mi < 2; ++mi)
#pragma unroll
        for (int ni = 0; ni < 2; ++ni)
            acc[mi][ni] = (f32x4){0.f, 0.f, 0.f, 0.f};

    auto stage = [&](int buf, int k0) {
#pragma unroll
        for (int it = 0; it < 2; ++it) {
            const int sbase = it * 256 + wv * 64;   // wave-uniform
            const int slot = sbase + ln;
            const int r = slot >> 3, c = slot & 7;
            const int cs = c ^ (r & 7);
            gload16(embh + (size_t)(m0 + r) * H + k0 + cs * 8, &As[buf][sbase * 8]);
            gload16(Bsrc + (size_t)(n0 + r) * H + k0 + cs * 8, &Bs[buf][sbase * 8]);
        }
    };

    stage(0, 0);
    int cur = 0;
    for (int ks = 0; ks < 12; ++ks) {
        __syncthreads();
        if (ks < 11) stage(cur ^ 1, (ks + 1) * 64);
        bf16x8 af[2][2], bfr[2][2];
#pragma unroll
        for (int mi = 0; mi < 2; ++mi) {
            const int r = wr + mi * 16 + lr;
#pragma unroll
            for (int kc = 0; kc < 2; ++kc) {
                const int qs = (kc * 4 + ko) ^ (r & 7);
                af[kc][mi] = *(const bf16x8*)(&As[cur][r * 64 + qs * 8]);
            }
        }
#pragma unroll
        for (int ni = 0; ni < 2; ++ni) {
            const int r = wc + ni * 16 + lr;
#pragma unroll
            for (int kc = 0; kc < 2; ++kc) {
                const int qs = (kc * 4 + ko) ^ (r & 7);
                bfr[kc][ni] = *(const bf16x8*)(&Bs[cur][r * 64 + qs * 8]);
            }
        }
#pragma unroll
        for (int kc = 0; kc < 2; ++kc)
#pragma unroll
            for (int mi = 0; mi < 2; ++mi)
#pragma unroll
                for (int ni = 0; ni < 2; ++ni)
                    acc[mi][ni] = __builtin_amdgcn_mfma_f32_16x16x32_bf16(
                        af[kc][mi], bfr[kc][ni], acc[mi][ni], 0, 0, 0);
        cur ^= 1;
    }

    float cb[2];
#pragma unroll
    for (int ni = 0; ni < 2; ++ni)
        cb[ni] = (sel == 0) ? b_corr[n0 + wc + ni * 16 + lr] : 0.f;
#pragma unroll
    for (int mi = 0; mi < 2; ++mi)
#pragma unroll
        for (int ni = 0; ni < 2; ++ni) {
            const int m = m0 + wr + mi * 16 + ko * 4;
            const int n = n0 + wc + ni * 16 + lr;
#pragma unroll
            for (int rr = 0; rr < 4; ++rr)
                C[(size_t)(m + rr) * H + n] = acc[mi][ni][rr] + cb[ni];
        }
}

// ---------------------------------------------------------------------------
// k_tail: grid 241 x 512
//   [0,144)  : corres 16i x 64j tiles
//   [144,240): tag heads, 8 rows/block
//   240      : relh reduce + stage1 GEMV (all-LDS)
// ---------------------------------------------------------------------------
__global__ __launch_bounds__(512) void k_tail(
    const float* __restrict__ hfb, const float* __restrict__ hsb,
    const float* __restrict__ fusb, const float* __restrict__ relh_part,
    const float* __restrict__ b_relh, const float* __restrict__ tagbias_ws,
    const float* __restrict__ W_gc, const float* __restrict__ b_gc,
    const float* __restrict__ W_rj, const float* __restrict__ b_rj,
    const float* __restrict__ W_sub, const float* __restrict__ W_obj,
    float* __restrict__ out)
{
    __shared__ float pool[10752];   // 42 KB, carved per branch
    const int bid = blockIdx.x, tid = threadIdx.x;

    if (bid < 144) {
        float* hfT = pool;                 // [32][68]
        float* hsS = pool + 32 * 68;       // [16][36]
        const int b   = bid / 36;
        const int rem = bid % 36;
        const int i0  = (rem / 3) * 16;
        const int j0  = (rem % 3) * 64;
        const int ty = tid >> 5, tx = tid & 31;
        const int jr = tid >> 3, q8 = tid & 7;
        float acc0 = 0.f, acc1 = 0.f;

        for (int hc = 0; hc < H; hc += 32) {
            const float4 fv = *(const float4*)(hfb + (size_t)(b * LL + j0 + jr) * H + hc + q8 * 4);
            hfT[(q8 * 4 + 0) * 68 + jr] = fv.x;
            hfT[(q8 * 4 + 1) * 68 + jr] = fv.y;
            hfT[(q8 * 4 + 2) * 68 + jr] = fv.z;
            hfT[(q8 * 4 + 3) * 68 + jr] = fv.w;
            if (tid < 128) {
                const float4 sv = *(const float4*)(hsb + (size_t)(b * LL + i0 + jr) * H + hc + q8 * 4);
                *(float4*)&hsS[jr * 36 + q8 * 4] = sv;
            }
            __syncthreads();
#pragma unroll
            for (int kq = 0; kq < 8; ++kq) {
                const float4 s4 = *(const float4*)&hsS[ty * 36 + kq * 4];
                const float4 w4 = *(const float4*)(W_gc + hc + kq * 4);
#pragma unroll
                for (int x = 0; x < 4; ++x) {
                    const float2 f2 = *(const float2*)&hfT[(kq * 4 + x) * 68 + tx * 2];
                    const float sv = (&s4.x)[x];
                    const float wv = (&w4.x)[x];
                    acc0 += fmaxf(f2.x + sv, 0.f) * wv;
                    acc1 += fmaxf(f2.y + sv, 0.f) * wv;
                }
            }
            __syncthreads();
        }
        const float bg = b_gc[0];
        float* po = out + 4704 + (size_t)b * LL * LL + (size_t)(i0 + ty) * LL + j0 + tx * 2;
        po[0] = acc0 + bg;
        po[1] = acc1 + bg;
    } else if (bid < 240) {
        // ---- tag heads ----
        const int wave = tid >> 6, lane = tid & 63;
        const int r = (bid - 144) * 8 + wave;
        const int b = r / LL;
        float a0 = 0, a1 = 0, a2 = 0, a3 = 0, a4 = 0, a5 = 0;
        for (int h = lane; h < H; h += 64) {
            const float f = fusb[(size_t)r * H + h];
            a0 += f * W_sub[h * 3 + 0]; a1 += f * W_sub[h * 3 + 1];
            a2 += f * W_sub[h * 3 + 2]; a3 += f * W_obj[h * 3 + 0];
            a4 += f * W_obj[h * 3 + 1]; a5 += f * W_obj[h * 3 + 2];
        }
#pragma unroll
        for (int off = 32; off > 0; off >>= 1) {
            a0 += __shfl_down(a0, off); a1 += __shfl_down(a1, off);
            a2 += __shfl_down(a2, off); a3 += __shfl_down(a3, off);
            a4 += __shfl_down(a4, off); a5 += __shfl_down(a5, off);
        }
        if (lane == 0) {
            out[96 + r * 3 + 0]   = a0 + tagbias_ws[b * 6 + 0];
            out[96 + r * 3 + 1]   = a1 + tagbias_ws[b * 6 + 1];
            out[96 + r * 3 + 2]   = a2 + tagbias_ws[b * 6 + 2];
            out[2400 + r * 3 + 0] = a3 + tagbias_ws[b * 6 + 3];
            out[2400 + r * 3 + 1] = a4 + tagbias_ws[b * 6 + 4];
            out[2400 + r * 3 + 2] = a5 + tagbias_ws[b * 6 + 5];
        }
    } else {
        // ---- relh reduce + stage1 GEMV, all LDS ----
        float* WrjS  = pool;           // 9216
        float* relhS = pool + 9216;    // 1536
        for (int i = tid; i < Hh * RR; i += 512) WrjS[i] = W_rj[i];
        for (int i = tid; i < 4 * Hh; i += 512) {
            const int b = i / Hh, o = i % Hh;
            float s = b_relh[o];
#pragma unroll
            for (int kc = 0; kc < 8; ++kc)
                s += relh_part[(size_t)(kc * 4 + b) * Hh + o];
            relhS[i] = fmaxf(s, 0.f);
        }
        __syncthreads();
        if (tid < 96) {
            const int b = tid / RR, rj = tid % RR;
            float s = b_rj[rj];
            for (int k = 0; k < Hh; ++k)
                s += relhS[b * Hh + k] * WrjS[k * RR + rj];
            out[b * RR + rj] = s;
        }
    }
}

extern "C" void kernel_launch(void* const* d_in, const int* in_sizes, int n_in,
                              void* d_out, int out_size, void* d_ws, size_t ws_size,
                              hipStream_t stream) {
    const float* emb    = (const float*)d_in[0];
    const int*   mask   = (const int*)d_in[1];
    const int*   trel   = (const int*)d_in[2];
    const float* W_relh = (const float*)d_in[3];
    const float* b_relh = (const float*)d_in[4];
    const float* W_rj   = (const float*)d_in[5];
    const float* b_rj   = (const float*)d_in[6];
    const float* W_corr = (const float*)d_in[7];
    const float* b_corr = (const float*)d_in[8];
    const float* W_gc   = (const float*)d_in[9];
    const float* b_gc   = (const float*)d_in[10];
    const float* relemb = (const float*)d_in[11];
    const float* W_tag  = (const float*)d_in[12];
    const float* b_tag  = (const float*)d_in[13];
    const float* W_sub  = (const float*)d_in[14];
    const float* b_sub  = (const float*)d_in[15];
    const float* W_obj  = (const float*)d_in[16];
    const float* b_obj  = (const float*)d_in[17];

    float* out = (float*)d_out;
    float* ws  = (float*)d_ws;
    float* hfb  = ws;
    float* hsb  = ws + (size_t)HH;
    float* fusb = ws + (size_t)2 * HH;
    unsigned short* embh = (unsigned short*)(ws + (size_t)3 * HH);
    unsigned short* wct0 = embh + (size_t)HH;
    unsigned short* wct1 = wct0 + (size_t)HH;
    unsigned short* wtt  = wct1 + (size_t)HH;
    float* avg_ws     = ws + (size_t)5 * HH;       // 4*768
    float* rp_part    = avg_ws + 4 * H;            // 8*4*768
    float* relh_part  = rp_part + 32 * H;          // 8*4*384
    float* tagbias_ws = relh_part + 32 * Hh;       // 4*6

    k_pre<<<1224, 256, 0, stream>>>(emb, mask, trel, W_corr, W_tag, relemb,
                                    avg_ws, rp_part, embh, wct0, wct1, wtt);
    k_main<<<625, 256, 0, stream>>>(embh, wct0, wct1, wtt, b_corr,
                                    W_relh, avg_ws, rp_part, b_tag,
                                    W_sub, b_sub, W_obj, b_obj,
                                    hfb, hsb, fusb, relh_part, tagbias_ws);
    k_tail<<<241, 512, 0, stream>>>(hfb, hsb, fusb, relh_part, b_relh, tagbias_ws,
                                    W_gc, b_gc, W_rj, b_rj,
                                    W_sub, W_obj, out);
}

// Round 5
// 58.404 us; speedup vs baseline: 2.2123x; 1.4493x over previous
//
#include <hip/hip_runtime.h>

#define H   768
#define Hh  384
#define LL  192
#define RR  24
#define HH  589824   // 768*768

typedef __attribute__((ext_vector_type(8))) short bf16x8;
typedef __attribute__((ext_vector_type(4))) float f32x4;

__device__ __forceinline__ unsigned short f2bf(float f) {
    unsigned int u = __float_as_uint(f);
    return (unsigned short)((u + 0x7FFF + ((u >> 16) & 1)) >> 16);  // RNE
}

__device__ __forceinline__ void gload16(const void* g, void* l) {
    __builtin_amdgcn_global_load_lds(
        (const __attribute__((address_space(1))) unsigned int*)g,
        (__attribute__((address_space(3))) unsigned int*)l, 16, 0, 0);
}

// ---------------------------------------------------------------------------
// k_pre: grid 1224 x 256  (unchanged from R4)
// ---------------------------------------------------------------------------
__global__ __launch_bounds__(256) void k_pre(
    const float* __restrict__ emb, const int* __restrict__ mask,
    const int* __restrict__ target_rel,
    const float* __restrict__ W_corr, const float* __restrict__ W_tag,
    const float* __restrict__ rel_emb,
    float* __restrict__ avg_ws, float* __restrict__ rp_part,
    unsigned short* __restrict__ embh, unsigned short* __restrict__ wct0,
    unsigned short* __restrict__ wct1, unsigned short* __restrict__ wtt)
{
    const int bid = blockIdx.x, tid = threadIdx.x;

    if (bid < 24) {
        __shared__ float msk[LL];
        __shared__ float part[32];
        __shared__ float msumS;
        __shared__ float4 red4[8][32];
        const int b  = bid / 6;
        const int h0 = (bid % 6) * 128;
        const int tx = tid & 31, ty = tid >> 5;
        if (tid < LL) msk[tid] = (float)mask[b * LL + tid];
        __syncthreads();
        if (tid < 32) {
            float s = 0.f;
            for (int k = tid; k < LL; k += 32) s += msk[k];
            part[tid] = s;
        }
        __syncthreads();
        if (tid == 0) {
            float s = 0.f;
            for (int k = 0; k < 32; ++k) s += part[k];
            msumS = s;
        }
        float4 acc = make_float4(0.f, 0.f, 0.f, 0.f);
        for (int l = ty; l < LL; l += 8) {
            const float m = msk[l];
            const float4 v = *(const float4*)(emb + (size_t)(b * LL + l) * H + h0 + tx * 4);
            acc.x += v.x * m; acc.y += v.y * m; acc.z += v.z * m; acc.w += v.w * m;
        }
        red4[ty][tx] = acc;
        __syncthreads();
        if (tid < 32) {
            float4 s = red4[0][tid];
#pragma unroll
            for (int r = 1; r < 8; ++r) {
                s.x += red4[r][tid].x; s.y += red4[r][tid].y;
                s.z += red4[r][tid].z; s.w += red4[r][tid].w;
            }
            const float inv = 1.f / msumS;
            s.x *= inv; s.y *= inv; s.z *= inv; s.w *= inv;
            *(float4*)(avg_ws + (size_t)b * H + h0 + tid * 4) = s;
        }
        return;
    }

    if (bid < 216) {
        __shared__ float red2[2][128];
        const int rb = bid - 24;
        const int kc = rb & 7;
        const int t2 = rb >> 3;
        const int b  = t2 / 6;
        const int n0 = (t2 % 6) * 128;
        const int n  = n0 + (tid & 127);
        const int strip = tid >> 7;
        const float* re = rel_emb + (size_t)target_rel[b] * H;
        const int h0 = kc * 96 + strip * 48;
        float s = 0.f;
        for (int h = h0; h < h0 + 48; ++h)
            s += re[h] * W_tag[(size_t)h * H + n];
        red2[strip][tid & 127] = s;
        __syncthreads();
        if (tid < 128)
            rp_part[(size_t)(kc * 4 + b) * H + n0 + tid] = red2[0][tid] + red2[1][tid];
        return;
    }

    if (bid < 360) {
        const size_t t = (size_t)(bid - 216) * 256 + tid;
        const float* s = emb + t * 16;
        union { unsigned short u[16]; uint4 v[2]; } pk;
#pragma unroll
        for (int q = 0; q < 4; ++q) {
            const float4 v = *(const float4*)(s + q * 4);
            pk.u[q * 4 + 0] = f2bf(v.x); pk.u[q * 4 + 1] = f2bf(v.y);
            pk.u[q * 4 + 2] = f2bf(v.z); pk.u[q * 4 + 3] = f2bf(v.w);
        }
        *(uint4*)(embh + t * 16)     = pk.v[0];
        *(uint4*)(embh + t * 16 + 8) = pk.v[1];
        return;
    }

    const int local = bid - 360;
    const int m  = local / 288;
    const int r2 = local % 288;
    const int ko = r2 / 3, nb = r2 % 3;
    const int n  = nb * 256 + tid;
    const float* src = (m == 0) ? W_corr : (m == 1) ? W_corr + HH : W_tag + HH;
    unsigned short* dst = (m == 0) ? wct0 : (m == 1) ? wct1 : wtt;
    union { unsigned short u[8]; uint4 v; } pk;
#pragma unroll
    for (int q = 0; q < 8; ++q)
        pk.u[q] = f2bf(src[(size_t)(ko * 8 + q) * H + n]);
    *(uint4*)(dst + (size_t)n * H + ko * 8) = pk.v;
}

// ---------------------------------------------------------------------------
// k_main: grid 625 x 256  (unchanged from R4)
// ---------------------------------------------------------------------------
__global__ __launch_bounds__(256) void k_main(
    const unsigned short* __restrict__ embh, const unsigned short* __restrict__ wct0,
    const unsigned short* __restrict__ wct1, const unsigned short* __restrict__ wtt,
    const float* __restrict__ b_corr,
    const float* __restrict__ W_relh, const float* __restrict__ avg_ws,
    const float* __restrict__ rp_part, const float* __restrict__ b_tag,
    const float* __restrict__ W_sub, const float* __restrict__ b_sub,
    const float* __restrict__ W_obj, const float* __restrict__ b_obj,
    float* __restrict__ hfb, float* __restrict__ hsb, float* __restrict__ fusb,
    float* __restrict__ relh_part, float* __restrict__ tagbias_ws)
{
    __shared__ unsigned short As[2][4096];
    __shared__ unsigned short Bs[2][4096];
    const int bid = blockIdx.x, tid = threadIdx.x;

    if (bid >= 432) {
        if (bid < 624) {
            float* red = (float*)&As[0][0];
            const int rb = bid - 432;
            const int kc = rb & 7;
            const int t2 = rb >> 3;
            const int b  = t2 / 6;
            const int o0 = (t2 % 6) * 64;
            const int tx = tid & 63, ty = tid >> 6;
            const int h0 = kc * 96 + ty * 24;
            float s = 0.f;
            for (int h = h0; h < h0 + 24; ++h)
                s += avg_ws[(size_t)b * H + h] * W_relh[(size_t)h * Hh + o0 + tx];
            red[ty * 64 + tx] = s;
            __syncthreads();
            if (ty == 0)
                relh_part[(size_t)(kc * 4 + b) * Hh + o0 + tx] =
                    red[tx] + red[64 + tx] + red[128 + tx] + red[192 + tx];
        } else {
            float* rpS = (float*)&As[0][0];
            for (int i = tid; i < 4 * H; i += 256) {
                const int b2 = i / H, n = i % H;
                float rv = b_tag[n];
#pragma unroll
                for (int kc = 0; kc < 8; ++kc)
                    rv += rp_part[(size_t)(kc * 4 + b2) * H + n];
                rpS[i] = rv;
            }
            __syncthreads();
            const int b = tid >> 6, ln = tid & 63;
            float a0 = 0, a1 = 0, a2 = 0, a3 = 0, a4 = 0, a5 = 0;
            for (int n = ln; n < H; n += 64) {
                const float rv = rpS[b * H + n];
                a0 += rv * W_sub[n * 3 + 0]; a1 += rv * W_sub[n * 3 + 1];
                a2 += rv * W_sub[n * 3 + 2]; a3 += rv * W_obj[n * 3 + 0];
                a4 += rv * W_obj[n * 3 + 1]; a5 += rv * W_obj[n * 3 + 2];
            }
#pragma unroll
            for (int off = 32; off > 0; off >>= 1) {
                a0 += __shfl_down(a0, off); a1 += __shfl_down(a1, off);
                a2 += __shfl_down(a2, off); a3 += __shfl_down(a3, off);
                a4 += __shfl_down(a4, off); a5 += __shfl_down(a5, off);
            }
            if (ln == 0) {
                tagbias_ws[b * 6 + 0] = a0 + b_sub[0];
                tagbias_ws[b * 6 + 1] = a1 + b_sub[1];
                tagbias_ws[b * 6 + 2] = a2 + b_sub[2];
                tagbias_ws[b * 6 + 3] = a3 + b_obj[0];
                tagbias_ws[b * 6 + 4] = a4 + b_obj[1];
                tagbias_ws[b * 6 + 5] = a5 + b_obj[2];
            }
        }
        return;
    }

    const int sel = bid / 144;
    const int tt  = bid % 144;
    const int mt = tt % 12, nt = tt / 12;
    const int m0 = mt * 64, n0 = nt * 64;
    const unsigned short* Bsrc = (sel == 0) ? wct0 : (sel == 1) ? wct1 : wtt;
    float* C = (sel == 0) ? hfb : (sel == 1) ? hsb : fusb;

    const int wv = tid >> 6, ln = tid & 63;
    const int lr = ln & 15, ko = ln >> 4;
    const int wr = (wv >> 1) * 32, wc = (wv & 1) * 32;

    f32x4 acc[2][2];
#pragma unroll
    for (int mi = 0; mi < 2; ++mi)
#pragma unroll
        for (int ni = 0; ni < 2; ++ni)
            acc[mi][ni] = (f32x4){0.f, 0.f, 0.f, 0.f};

    auto stage = [&](int buf, int k0) {
#pragma unroll
        for (int it = 0; it < 2; ++it) {
            const int sbase = it * 256 + wv * 64;
            const int slot = sbase + ln;
            const int r = slot >> 3, c = slot & 7;
            const int cs = c ^ (r & 7);
            gload16(embh + (size_t)(m0 + r) * H + k0 + cs * 8, &As[buf][sbase * 8]);
            gload16(Bsrc + (size_t)(n0 + r) * H + k0 + cs * 8, &Bs[buf][sbase * 8]);
        }
    };

    stage(0, 0);
    int cur = 0;
    for (int ks = 0; ks < 12; ++ks) {
        __syncthreads();
        if (ks < 11) stage(cur ^ 1, (ks + 1) * 64);
        bf16x8 af[2][2], bfr[2][2];
#pragma unroll
        for (int mi = 0; mi < 2; ++mi) {
            const int r = wr + mi * 16 + lr;
#pragma unroll
            for (int kc = 0; kc < 2; ++kc) {
                const int qs = (kc * 4 + ko) ^ (r & 7);
                af[kc][mi] = *(const bf16x8*)(&As[cur][r * 64 + qs * 8]);
            }
        }
#pragma unroll
        for (int ni = 0; ni < 2; ++ni) {
            const int r = wc + ni * 16 + lr;
#pragma unroll
            for (int kc = 0; kc < 2; ++kc) {
                const int qs = (kc * 4 + ko) ^ (r & 7);
                bfr[kc][ni] = *(const bf16x8*)(&Bs[cur][r * 64 + qs * 8]);
            }
        }
#pragma unroll
        for (int kc = 0; kc < 2; ++kc)
#pragma unroll
            for (int mi = 0; mi < 2; ++mi)
#pragma unroll
                for (int ni = 0; ni < 2; ++ni)
                    acc[mi][ni] = __builtin_amdgcn_mfma_f32_16x16x32_bf16(
                        af[kc][mi], bfr[kc][ni], acc[mi][ni], 0, 0, 0);
        cur ^= 1;
    }

    float cb[2];
#pragma unroll
    for (int ni = 0; ni < 2; ++ni)
        cb[ni] = (sel == 0) ? b_corr[n0 + wc + ni * 16 + lr] : 0.f;
#pragma unroll
    for (int mi = 0; mi < 2; ++mi)
#pragma unroll
        for (int ni = 0; ni < 2; ++ni) {
            const int m = m0 + wr + mi * 16 + ko * 4;
            const int n = n0 + wc + ni * 16 + lr;
#pragma unroll
            for (int rr = 0; rr < 4; ++rr)
                C[(size_t)(m + rr) * H + n] = acc[mi][ni][rr] + cb[ni];
        }
}

// ---------------------------------------------------------------------------
// k_tail: grid 1153 x 256
//   [0,576)    : corres ABS-part partials. tile 16i x 64j, h-chunk 192 (4-way
//                split). relu(x)w = 0.5(xw + |x|w): here accumulate |x|w only.
//   [576,768)  : tag heads, 4 rows/block
//   [768,1152) : hfw/hsw rank-1 GEMVs (1536 rows, wave per row)
//   1152       : relh reduce + stage1 GEMV
// ---------------------------------------------------------------------------
__global__ __launch_bounds__(256) void k_tail(
    const float* __restrict__ hfb, const float* __restrict__ hsb,
    const float* __restrict__ fusb, const float* __restrict__ relh_part,
    const float* __restrict__ b_relh, const float* __restrict__ tagbias_ws,
    const float* __restrict__ W_gc,
    const float* __restrict__ W_rj, const float* __restrict__ b_rj,
    const float* __restrict__ W_sub, const float* __restrict__ W_obj,
    float* __restrict__ cpart, float* __restrict__ hfw_ws,
    float* __restrict__ out)
{
    __shared__ float pool[2752];   // 11 KB: hfT[32][68] + hsS[16][36]
    const int bid = blockIdx.x, tid = threadIdx.x;

    if (bid < 576) {
        float* hfT = pool;               // [32][68]  [kk][j]
        float* hsS = pool + 2176;        // [16][36]  [i][kk]
        const int hc4  = bid & 3;
        const int tile = bid >> 2;       // 0..143
        const int b   = tile / 36;
        const int rem = tile % 36;
        const int i0  = (rem / 3) * 16;
        const int j0  = (rem % 3) * 64;
        const int tx = tid & 15, ty = tid >> 4;   // j-quad, i
        const int q8 = tid & 7;
        float a0 = 0.f, a1 = 0.f, a2 = 0.f, a3 = 0.f;

        for (int ch = 0; ch < 6; ++ch) {
            const int hc = hc4 * 192 + ch * 32;
#pragma unroll
            for (int it = 0; it < 2; ++it) {
                const int row = it * 32 + (tid >> 3);
                const float4 fv = *(const float4*)(hfb + (size_t)(b * LL + j0 + row) * H + hc + q8 * 4);
                hfT[(q8 * 4 + 0) * 68 + row] = fv.x;
                hfT[(q8 * 4 + 1) * 68 + row] = fv.y;
                hfT[(q8 * 4 + 2) * 68 + row] = fv.z;
                hfT[(q8 * 4 + 3) * 68 + row] = fv.w;
            }
            if (tid < 128) {
                const int row = tid >> 3;
                const float4 sv = *(const float4*)(hsb + (size_t)(b * LL + i0 + row) * H + hc + q8 * 4);
                *(float4*)&hsS[row * 36 + q8 * 4] = sv;
            }
            __syncthreads();
#pragma unroll
            for (int kq = 0; kq < 8; ++kq) {
                const float4 s4 = *(const float4*)&hsS[ty * 36 + kq * 4];
                const float4 w4 = *(const float4*)(W_gc + hc + kq * 4);
#pragma unroll
                for (int x = 0; x < 4; ++x) {
                    const float4 f4 = *(const float4*)&hfT[(kq * 4 + x) * 68 + tx * 4];
                    const float sv = (&s4.x)[x];
                    const float wv = (&w4.x)[x];
                    a0 += fabsf(f4.x + sv) * wv;
                    a1 += fabsf(f4.y + sv) * wv;
                    a2 += fabsf(f4.z + sv) * wv;
                    a3 += fabsf(f4.w + sv) * wv;
                }
            }
            __syncthreads();
        }
        float4 o = make_float4(a0, a1, a2, a3);
        *(float4*)(cpart + (size_t)hc4 * 147456 + (size_t)b * 36864
                   + (size_t)(i0 + ty) * LL + j0 + tx * 4) = o;
    } else if (bid < 768) {
        // ---- tag heads: 4 rows/block ----
        const int wave = tid >> 6, lane = tid & 63;
        const int r = (bid - 576) * 4 + wave;
        const int b = r / LL;
        float a0 = 0, a1 = 0, a2 = 0, a3 = 0, a4 = 0, a5 = 0;
        for (int h = lane; h < H; h += 64) {
            const float f = fusb[(size_t)r * H + h];
            a0 += f * W_sub[h * 3 + 0]; a1 += f * W_sub[h * 3 + 1];
            a2 += f * W_sub[h * 3 + 2]; a3 += f * W_obj[h * 3 + 0];
            a4 += f * W_obj[h * 3 + 1]; a5 += f * W_obj[h * 3 + 2];
        }
#pragma unroll
        for (int off = 32; off > 0; off >>= 1) {
            a0 += __shfl_down(a0, off); a1 += __shfl_down(a1, off);
            a2 += __shfl_down(a2, off); a3 += __shfl_down(a3, off);
            a4 += __shfl_down(a4, off); a5 += __shfl_down(a5, off);
        }
        if (lane == 0) {
            out[96 + r * 3 + 0]   = a0 + tagbias_ws[b * 6 + 0];
            out[96 + r * 3 + 1]   = a1 + tagbias_ws[b * 6 + 1];
            out[96 + r * 3 + 2]   = a2 + tagbias_ws[b * 6 + 2];
            out[2400 + r * 3 + 0] = a3 + tagbias_ws[b * 6 + 3];
            out[2400 + r * 3 + 1] = a4 + tagbias_ws[b * 6 + 4];
            out[2400 + r * 3 + 2] = a5 + tagbias_ws[b * 6 + 5];
        }
    } else if (bid < 1152) {
        // ---- rank-1 GEMVs: hfw (rows 0..767) / hsw (rows 768..1535) ----
        const int wave = tid >> 6, lane = tid & 63;
        const int idx = (bid - 768) * 4 + wave;
        const float* src = (idx < 768) ? (hfb + (size_t)idx * H)
                                       : (hsb + (size_t)(idx - 768) * H);
        float s = 0.f;
        for (int h = lane; h < H; h += 64)
            s += src[h] * W_gc[h];
#pragma unroll
        for (int off = 32; off > 0; off >>= 1)
            s += __shfl_down(s, off);
        if (lane == 0) hfw_ws[idx] = s;
    } else {
        // ---- relh reduce + stage1 GEMV ----
        float* relhS = pool;   // 1536 floats
        for (int i = tid; i < 4 * Hh; i += 256) {
            const int b = i / Hh, o = i % Hh;
            float s = b_relh[o];
#pragma unroll
            for (int kc = 0; kc < 8; ++kc)
                s += relh_part[(size_t)(kc * 4 + b) * Hh + o];
            relhS[i] = fmaxf(s, 0.f);
        }
        __syncthreads();
        if (tid < 96) {
            const int b = tid / RR, rj = tid % RR;
            float s = b_rj[rj];
            for (int k = 0; k < Hh; ++k)
                s += relhS[b * Hh + k] * W_rj[k * RR + rj];
            out[b * RR + rj] = s;
        }
    }
}

// ---------------------------------------------------------------------------
// k_merge: grid 144 x 256. out_corres = 0.5*(abs_psum + hfw[j] + hsw[i]) + bg
// ---------------------------------------------------------------------------
__global__ __launch_bounds__(256) void k_merge(
    const float* __restrict__ cpart, const float* __restrict__ hfw_ws,
    const float* __restrict__ b_gc, float* __restrict__ out)
{
    const int idx = blockIdx.x * 256 + threadIdx.x;   // 0..36863
    const int b  = idx / 9216;
    const int rr = idx % 9216;
    const int i  = rr / 48;
    const int j4 = (rr % 48) * 4;
    const size_t off = (size_t)b * 36864 + (size_t)i * LL + j4;

    float4 p0 = *(const float4*)(cpart + off);
    float4 p1 = *(const float4*)(cpart + 147456 + off);
    float4 p2 = *(const float4*)(cpart + 2 * 147456 + off);
    float4 p3 = *(const float4*)(cpart + 3 * 147456 + off);
    const float4 hw = *(const float4*)(hfw_ws + b * LL + j4);
    const float hs = hfw_ws[768 + b * LL + i];
    const float bg = b_gc[0];

    float4 o;
    o.x = 0.5f * (p0.x + p1.x + p2.x + p3.x + hw.x + hs) + bg;
    o.y = 0.5f * (p0.y + p1.y + p2.y + p3.y + hw.y + hs) + bg;
    o.z = 0.5f * (p0.z + p1.z + p2.z + p3.z + hw.z + hs) + bg;
    o.w = 0.5f * (p0.w + p1.w + p2.w + p3.w + hw.w + hs) + bg;
    *(float4*)(out + 4704 + off) = o;
}

extern "C" void kernel_launch(void* const* d_in, const int* in_sizes, int n_in,
                              void* d_out, int out_size, void* d_ws, size_t ws_size,
                              hipStream_t stream) {
    const float* emb    = (const float*)d_in[0];
    const int*   mask   = (const int*)d_in[1];
    const int*   trel   = (const int*)d_in[2];
    const float* W_relh = (const float*)d_in[3];
    const float* b_relh = (const float*)d_in[4];
    const float* W_rj   = (const float*)d_in[5];
    const float* b_rj   = (const float*)d_in[6];
    const float* W_corr = (const float*)d_in[7];
    const float* b_corr = (const float*)d_in[8];
    const float* W_gc   = (const float*)d_in[9];
    const float* b_gc   = (const float*)d_in[10];
    const float* relemb = (const float*)d_in[11];
    const float* W_tag  = (const float*)d_in[12];
    const float* b_tag  = (const float*)d_in[13];
    const float* W_sub  = (const float*)d_in[14];
    const float* b_sub  = (const float*)d_in[15];
    const float* W_obj  = (const float*)d_in[16];
    const float* b_obj  = (const float*)d_in[17];

    float* out = (float*)d_out;
    float* ws  = (float*)d_ws;
    float* hfb  = ws;
    float* hsb  = ws + (size_t)HH;
    float* fusb = ws + (size_t)2 * HH;
    unsigned short* embh = (unsigned short*)(ws + (size_t)3 * HH);
    unsigned short* wct0 = embh + (size_t)HH;
    unsigned short* wct1 = wct0 + (size_t)HH;
    unsigned short* wtt  = wct1 + (size_t)HH;
    // cpart aliases embh/wct0 (dead after k_main): HH floats at ws+3HH
    float* cpart = ws + (size_t)3 * HH;
    float* avg_ws     = ws + (size_t)5 * HH;       // 4*768
    float* rp_part    = avg_ws + 4 * H;            // 8*4*768
    float* relh_part  = rp_part + 32 * H;          // 8*4*384
    float* tagbias_ws = relh_part + 32 * Hh;       // 4*6
    float* hfw_ws     = tagbias_ws + 24;           // 1536

    k_pre<<<1224, 256, 0, stream>>>(emb, mask, trel, W_corr, W_tag, relemb,
                                    avg_ws, rp_part, embh, wct0, wct1, wtt);
    k_main<<<625, 256, 0, stream>>>(embh, wct0, wct1, wtt, b_corr,
                                    W_relh, avg_ws, rp_part, b_tag,
                                    W_sub, b_sub, W_obj, b_obj,
                                    hfb, hsb, fusb, relh_part, tagbias_ws);
    k_tail<<<1153, 256, 0, stream>>>(hfb, hsb, fusb, relh_part, b_relh, tagbias_ws,
                                     W_gc, W_rj, b_rj, W_sub, W_obj,
                                     cpart, hfw_ws, out);
    k_merge<<<144, 256, 0, stream>>>(cpart, hfw_ws, b_gc, out);
}